// Round 1
// baseline (533.374 us; speedup 1.0000x reference)
//
#include <hip/hip_runtime.h>

#define DIM 128
#define HID 32

// ---------------------------------------------------------------------------
// Kernel 1: wsum[k] = sum_d W[k][d]   (the einsum 'ed,ef->e' collapses the
// bilinear term to (z_src . wsum) * (sum z_dst) -- see launch notes)
// ---------------------------------------------------------------------------
__global__ void wsum_kernel(const float* __restrict__ W, float* __restrict__ wsum)
{
    int k = threadIdx.x;                 // 128 threads, one W row each
    const float4* row = (const float4*)(W + (size_t)k * DIM);
    float s = 0.f;
#pragma unroll
    for (int i = 0; i < DIM / 4; i++) {
        float4 v = row[i];
        s += v.x + v.y + v.z + v.w;
    }
    wsum[k] = s;
}

// ---------------------------------------------------------------------------
// Kernel 2: per-node precompute
//   za[n][h] = sum_k z[n][k] * w1[k][h]          (w1 rows 0..127)
//   zb[n][h] = sum_k z[n][k] * w1[128+k][h]      (w1 rows 128..255)
//   s1[n]    = sum_k z[n][k] * wsum[k]
//   s2[n]    = sum_k z[n][k]
// block = 256 threads, 64 nodes/block. Thread (h = tid&31, ng = tid>>5)
// owns h-column for 8 nodes; z reads are (near-)wave-uniform float4 -> L1 hot.
// ---------------------------------------------------------------------------
__global__ __launch_bounds__(256) void node_precompute(
    const float* __restrict__ z, const float* __restrict__ w1,
    const float* __restrict__ wsum,
    float* __restrict__ za, float* __restrict__ zb,
    float* __restrict__ s1, float* __restrict__ s2, int nNodes)
{
    const int tid = threadIdx.x;
    const int h  = tid & 31;
    const int ng = tid >> 5;                       // 0..7
    const int node0 = blockIdx.x * 64 + ng * 8;

    float accA[8], accB[8], accS[8], accZ[8];
#pragma unroll
    for (int i = 0; i < 8; i++) { accA[i] = 0.f; accB[i] = 0.f; accS[i] = 0.f; accZ[i] = 0.f; }

    for (int k4 = 0; k4 < DIM / 4; k4++) {
        const int k = k4 * 4;
        float4 ws4 = *(const float4*)(wsum + k);
        float wa0 = w1[(k + 0) * HID + h];
        float wa1 = w1[(k + 1) * HID + h];
        float wa2 = w1[(k + 2) * HID + h];
        float wa3 = w1[(k + 3) * HID + h];
        float wb0 = w1[(DIM + k + 0) * HID + h];
        float wb1 = w1[(DIM + k + 1) * HID + h];
        float wb2 = w1[(DIM + k + 2) * HID + h];
        float wb3 = w1[(DIM + k + 3) * HID + h];
#pragma unroll
        for (int i = 0; i < 8; i++) {
            int n = node0 + i;
            if (n >= nNodes) n = nNodes - 1;       // clamp (stores are guarded)
            float4 zv = *(const float4*)(z + (size_t)n * DIM + k);
            accA[i] += zv.x * wa0 + zv.y * wa1 + zv.z * wa2 + zv.w * wa3;
            accB[i] += zv.x * wb0 + zv.y * wb1 + zv.z * wb2 + zv.w * wb3;
            accS[i] += zv.x * ws4.x + zv.y * ws4.y + zv.z * ws4.z + zv.w * ws4.w;
            accZ[i] += zv.x + zv.y + zv.z + zv.w;
        }
    }

#pragma unroll
    for (int i = 0; i < 8; i++) {
        int n = node0 + i;
        if (n < nNodes) {
            za[(size_t)n * HID + h] = accA[i];
            zb[(size_t)n * HID + h] = accB[i];
            if (h == 0) { s1[n] = accS[i]; s2[n] = accZ[i]; }
        }
    }
}

// ---------------------------------------------------------------------------
// Kernel 3: per-edge. One thread per edge.
//   bil    = s1[src] * s2[dst] + bias
//   hacc_h = sum_d zs[d]*zd[d]*w1c[d][h]   (w1c = w1 rows 256..383)
//   out    = bil + sum_h relu(hacc_h + za[src][h] + zb[dst][h] + b1[h]) * w2[h]
// w1c addresses are wave-uniform (loop-counter indexed) -> scalar/broadcast
// loads, L1-resident; only z/za/zb reads are true gathers (L2/L3-resident).
// ---------------------------------------------------------------------------
__global__ __launch_bounds__(256) void edge_kernel(
    const float* __restrict__ z, const int* __restrict__ ei,
    const float* __restrict__ za, const float* __restrict__ zb,
    const float* __restrict__ s1, const float* __restrict__ s2,
    const float* __restrict__ w1, const float* __restrict__ b1,
    const float* __restrict__ w2, const float* __restrict__ b2,
    const float* __restrict__ bias, float* __restrict__ out, int nE)
{
    int e = blockIdx.x * 256 + threadIdx.x;
    if (e >= nE) return;
    const int src = ei[e];
    const int dst = ei[nE + e];

    const float4* zs4 = (const float4*)(z + (size_t)src * DIM);
    const float4* zd4 = (const float4*)(z + (size_t)dst * DIM);
    const float4* w1c = (const float4*)(w1 + 256 * HID);   // [128][32], float4 stride 8

    float hacc[HID];
#pragma unroll
    for (int i = 0; i < HID; i++) hacc[i] = 0.f;

    for (int d4 = 0; d4 < DIM / 4; d4++) {
        float4 a = zs4[d4];
        float4 b = zd4[d4];
        float p0 = a.x * b.x, p1 = a.y * b.y, p2 = a.z * b.z, p3 = a.w * b.w;
        const float4* r0 = w1c + (size_t)(d4 * 4 + 0) * (HID / 4);
        const float4* r1 = w1c + (size_t)(d4 * 4 + 1) * (HID / 4);
        const float4* r2 = w1c + (size_t)(d4 * 4 + 2) * (HID / 4);
        const float4* r3 = w1c + (size_t)(d4 * 4 + 3) * (HID / 4);
#pragma unroll
        for (int h4 = 0; h4 < HID / 4; h4++) {
            float4 q0 = r0[h4], q1 = r1[h4], q2 = r2[h4], q3 = r3[h4];
            hacc[h4 * 4 + 0] += p0 * q0.x + p1 * q1.x + p2 * q2.x + p3 * q3.x;
            hacc[h4 * 4 + 1] += p0 * q0.y + p1 * q1.y + p2 * q2.y + p3 * q3.y;
            hacc[h4 * 4 + 2] += p0 * q0.z + p1 * q1.z + p2 * q2.z + p3 * q3.z;
            hacc[h4 * 4 + 3] += p0 * q0.w + p1 * q1.w + p2 * q2.w + p3 * q3.w;
        }
    }

    float mlp = 0.f;
    const float4* zah = (const float4*)(za + (size_t)src * HID);
    const float4* zbh = (const float4*)(zb + (size_t)dst * HID);
    const float4* b14 = (const float4*)b1;
    const float4* w24 = (const float4*)w2;
#pragma unroll
    for (int h4 = 0; h4 < HID / 4; h4++) {
        float4 A = zah[h4], B = zbh[h4], C = b14[h4], D = w24[h4];
        float v;
        v = hacc[h4 * 4 + 0] + A.x + B.x + C.x; mlp += fmaxf(v, 0.f) * D.x;
        v = hacc[h4 * 4 + 1] + A.y + B.y + C.y; mlp += fmaxf(v, 0.f) * D.y;
        v = hacc[h4 * 4 + 2] + A.z + B.z + C.z; mlp += fmaxf(v, 0.f) * D.z;
        v = hacc[h4 * 4 + 3] + A.w + B.w + C.w; mlp += fmaxf(v, 0.f) * D.w;
    }

    float bil = s1[src] * s2[dst] + bias[0];
    out[e] = bil + mlp + b2[0];
}

// ---------------------------------------------------------------------------
// Launch. Workspace layout (floats):
//   za: nNodes*32 | zb: nNodes*32 | s1: nNodes | s2: nNodes | wsum: 128
// Total ~26.4 MB for nNodes=100000 (well under typical ws_size).
// ---------------------------------------------------------------------------
extern "C" void kernel_launch(void* const* d_in, const int* in_sizes, int n_in,
                              void* d_out, int out_size, void* d_ws, size_t ws_size,
                              hipStream_t stream)
{
    const float* z    = (const float*)d_in[0];
    const int*   ei   = (const int*)d_in[1];
    const float* W    = (const float*)d_in[2];
    const float* bias = (const float*)d_in[3];
    const float* w1   = (const float*)d_in[4];
    const float* b1   = (const float*)d_in[5];
    const float* w2   = (const float*)d_in[6];
    const float* b2   = (const float*)d_in[7];
    float* out = (float*)d_out;

    const int nNodes = in_sizes[0] / DIM;
    const int nE = out_size;

    float* za   = (float*)d_ws;
    float* zb   = za + (size_t)nNodes * HID;
    float* s1   = zb + (size_t)nNodes * HID;
    float* s2   = s1 + nNodes;
    float* wsum = s2 + nNodes;

    wsum_kernel<<<1, 128, 0, stream>>>(W, wsum);

    int preBlocks = (nNodes + 63) / 64;
    node_precompute<<<preBlocks, 256, 0, stream>>>(z, w1, wsum, za, zb, s1, s2, nNodes);

    int edgeBlocks = (nE + 255) / 256;
    edge_kernel<<<edgeBlocks, 256, 0, stream>>>(z, ei, za, zb, s1, s2,
                                                w1, b1, w2, b2, bias, out, nE);
}

// Round 2
// 188.422 us; speedup vs baseline: 2.8307x; 2.8307x over previous
//
#include <hip/hip_runtime.h>

#define DIM 128
#define HID 32
#define EPT 32            // edges per tile in edge_kernel
#define KTOT 384          // 3*DIM
#define PSTR 392          // padded LDS row stride (bf16 elems): 392*2B=784B, %128B!=0 -> 2-way-max banks

typedef __attribute__((ext_vector_type(8))) unsigned short u16x8;
typedef __bf16 bf16x8 __attribute__((ext_vector_type(8)));
typedef __attribute__((ext_vector_type(4))) float f32x4;

static __device__ inline float b2f(unsigned short u) {
    return __uint_as_float(((unsigned)u) << 16);
}
static __device__ inline unsigned short f2bf(float f) {
    unsigned u = __float_as_uint(f);
    return (unsigned short)((u + 0x7fff + ((u >> 16) & 1)) >> 16);  // RNE
}

// ---------------------------------------------------------------------------
// Kernel 0: wsum[k] = sum_d W[k][d]  (einsum 'ed,ef->e' factorizes:
//  bilinear[e] = (z_src . wsum) * (sum_f z_dst[f]) = s1[src]*s2[dst])
// ---------------------------------------------------------------------------
__global__ void wsum_kernel(const float* __restrict__ W, float* __restrict__ wsum)
{
    int k = threadIdx.x;
    const float4* row = (const float4*)(W + (size_t)k * DIM);
    float s = 0.f;
#pragma unroll
    for (int i = 0; i < DIM / 4; i++) {
        float4 v = row[i];
        s += v.x + v.y + v.z + v.w;
    }
    wsum[k] = s;
}

// ---------------------------------------------------------------------------
// Kernel 1: per-node: zb16[n][:] = bf16(z[n][:]), s1[n] = z.wsum, s2[n] = sum z
// 4 threads per node (32 elems each); fully coalesced f32 reads.
// ---------------------------------------------------------------------------
__global__ __launch_bounds__(256) void node_precompute(
    const float* __restrict__ z, const float* __restrict__ wsum,
    unsigned short* __restrict__ zb16,
    float* __restrict__ s1, float* __restrict__ s2, int nNodes)
{
    const int tid = threadIdx.x;
    const int n = blockIdx.x * 64 + (tid >> 2);
    const int q = tid & 3;
    if (n >= nNodes) return;                      // whole node-quad exits together

    const float* zr = z + (size_t)n * DIM + q * 32;
    const float* wr = wsum + q * 32;
    unsigned short* zo = zb16 + (size_t)n * DIM + q * 32;

    float a1 = 0.f, a2 = 0.f;
#pragma unroll
    for (int i = 0; i < 4; i++) {                 // 4 x 8 floats
        float4 v0 = *(const float4*)(zr + i * 8);
        float4 v1 = *(const float4*)(zr + i * 8 + 4);
        float4 w0 = *(const float4*)(wr + i * 8);
        float4 w1v = *(const float4*)(wr + i * 8 + 4);
        a1 += v0.x * w0.x + v0.y * w0.y + v0.z * w0.z + v0.w * w0.w
            + v1.x * w1v.x + v1.y * w1v.y + v1.z * w1v.z + v1.w * w1v.w;
        a2 += v0.x + v0.y + v0.z + v0.w + v1.x + v1.y + v1.z + v1.w;
        u16x8 o;
        o[0] = f2bf(v0.x); o[1] = f2bf(v0.y); o[2] = f2bf(v0.z); o[3] = f2bf(v0.w);
        o[4] = f2bf(v1.x); o[5] = f2bf(v1.y); o[6] = f2bf(v1.z); o[7] = f2bf(v1.w);
        *(u16x8*)(zo + i * 8) = o;
    }
    a1 += __shfl_xor(a1, 1); a1 += __shfl_xor(a1, 2);
    a2 += __shfl_xor(a2, 1); a2 += __shfl_xor(a2, 2);
    if (q == 0) { s1[n] = a1; s2[n] = a2; }
}

// ---------------------------------------------------------------------------
// Kernel 2: per-edge, persistent blocks, 32 edges/tile, MFMA contraction.
//  feat[e] = [zs | zd | zs*zd] (bf16, staged in LDS, coalesced row gathers)
//  hacc[e][h] = feat[e] @ w1  via mfma_f32_16x16x32_bf16 (A=feat, B^T=w1T rows)
//  out[e] = s1[src]*s2[dst] + bias + b2 + sum_h relu(hacc+b1[h])*w2[h]
// ---------------------------------------------------------------------------
__global__ __launch_bounds__(256) void edge_kernel(
    const unsigned short* __restrict__ zb16, const int* __restrict__ ei,
    const float* __restrict__ s1, const float* __restrict__ s2,
    const float* __restrict__ w1, const float* __restrict__ b1,
    const float* __restrict__ w2, const float* __restrict__ b2,
    const float* __restrict__ bias, float* __restrict__ out,
    int nE, int nTiles)
{
    __shared__ unsigned short sP[EPT][PSTR];   // feature rows (K=384 used)
    __shared__ unsigned short sW[HID][PSTR];   // w1^T rows: sW[h][k] = w1[k][h]
    __shared__ int   sSrc[EPT], sDst[EPT];
    __shared__ float sBil[EPT];
    __shared__ float sAcc[2][EPT];

    const int tid  = threadIdx.x;
    const int lane = tid & 63;
    const int wv   = tid >> 6;          // 0..3
    const int m_tile = wv >> 1;         // edge-tile half (16 edges)
    const int n_tile = wv & 1;          // h-tile half (16 h)
    const int quad = lane >> 4;         // 0..3
    const int l15  = lane & 15;

    // stage w1^T once per block (persistent)
    for (int i = tid; i < KTOT * HID; i += 256) {
        int k = i >> 5, h = i & 31;
        sW[h][k] = f2bf(w1[i]);
    }
    const int h_lane = n_tile * 16 + l15;
    const float b1h = b1[h_lane];
    const float w2h = w2[h_lane];
    const float cbias = bias[0] + b2[0];
    __syncthreads();

    for (int tile = blockIdx.x; tile < nTiles; tile += gridDim.x) {
        const int e0 = tile * EPT;
        // phase 1: indices + bilinear scalar
        if (tid < EPT) {
            int e = e0 + tid;
            int s = 0, d = 0;
            if (e < nE) { s = ei[e]; d = ei[nE + e]; }
            sSrc[tid] = s; sDst[tid] = d;
            sBil[tid] = s1[s] * s2[d];
        }
        __syncthreads();

        // phase 2: gather rows (coalesced 16 lanes x 16B = full 256B row) + product
        {
            const int l  = tid & 15;
            const int eh = tid >> 4;            // 0..15
#pragma unroll
            for (int p = 0; p < 2; p++) {
                const int el = p * 16 + eh;
                const int s = sSrc[el], d = sDst[el];
                u16x8 zs = *(const u16x8*)(zb16 + (size_t)s * DIM + l * 8);
                u16x8 zd = *(const u16x8*)(zb16 + (size_t)d * DIM + l * 8);
                u16x8 pr;
#pragma unroll
                for (int j = 0; j < 8; j++) pr[j] = f2bf(b2f(zs[j]) * b2f(zd[j]));
                *(u16x8*)(&sP[el][l * 8])       = zs;
                *(u16x8*)(&sP[el][128 + l * 8]) = zd;
                *(u16x8*)(&sP[el][256 + l * 8]) = pr;
            }
        }
        __syncthreads();

        // phase 3: MFMA over K=384 (12 steps). A: sP rows; B^T: sW rows.
        f32x4 acc = {0.f, 0.f, 0.f, 0.f};
        const unsigned short* arow = &sP[m_tile * 16 + l15][quad * 8];
        const unsigned short* brow = &sW[n_tile * 16 + l15][quad * 8];
#pragma unroll
        for (int k = 0; k < 12; k++) {
            bf16x8 a = *(const bf16x8*)(arow + k * 32);
            bf16x8 b = *(const bf16x8*)(brow + k * 32);
            acc = __builtin_amdgcn_mfma_f32_16x16x32_bf16(a, b, acc, 0, 0, 0);
        }
        // epilogue: C/D layout col=lane&15 (h), row=quad*4+r (edge)
#pragma unroll
        for (int r = 0; r < 4; r++) {
            float v = fmaxf(acc[r] + b1h, 0.f) * w2h;
            v += __shfl_xor(v, 1); v += __shfl_xor(v, 2);
            v += __shfl_xor(v, 4); v += __shfl_xor(v, 8);
            if (l15 == 0) sAcc[n_tile][m_tile * 16 + quad * 4 + r] = v;
        }
        __syncthreads();

        // phase 4: write out
        if (tid < EPT) {
            int e = e0 + tid;
            if (e < nE)
                out[e] = sBil[tid] + cbias + sAcc[0][tid] + sAcc[1][tid];
        }
        __syncthreads();   // protect LDS before next tile overwrites
    }
}

// ---------------------------------------------------------------------------
// Workspace (from d_ws): zb16 ushort[nNodes*128] | s1[nNodes] | s2[nNodes] | wsum[128]
// ~26.4 MB for nNodes=100000.
// ---------------------------------------------------------------------------
extern "C" void kernel_launch(void* const* d_in, const int* in_sizes, int n_in,
                              void* d_out, int out_size, void* d_ws, size_t ws_size,
                              hipStream_t stream)
{
    const float* z    = (const float*)d_in[0];
    const int*   ei   = (const int*)d_in[1];
    const float* W    = (const float*)d_in[2];
    const float* bias = (const float*)d_in[3];
    const float* w1   = (const float*)d_in[4];
    const float* b1   = (const float*)d_in[5];
    const float* w2   = (const float*)d_in[6];
    const float* b2   = (const float*)d_in[7];
    float* out = (float*)d_out;

    const int nNodes = in_sizes[0] / DIM;
    const int nE = out_size;

    unsigned short* zb16 = (unsigned short*)d_ws;
    float* s1   = (float*)(zb16 + (size_t)nNodes * DIM);
    float* s2   = s1 + nNodes;
    float* wsum = s2 + nNodes;

    wsum_kernel<<<1, 128, 0, stream>>>(W, wsum);

    int preBlocks = (nNodes + 63) / 64;
    node_precompute<<<preBlocks, 256, 0, stream>>>(z, wsum, zb16, s1, s2, nNodes);

    const int nTiles = (nE + EPT - 1) / EPT;
    int grid = 768;                       // 3 blocks/CU (LDS ~50 KB) x 256 CUs
    if (grid > nTiles) grid = nTiles;
    edge_kernel<<<grid, 256, 0, stream>>>(zb16, ei, s1, s2,
                                          w1, b1, w2, b2, bias, out, nE, nTiles);
}

// Round 3
// 167.476 us; speedup vs baseline: 3.1848x; 1.1251x over previous
//
#include <hip/hip_runtime.h>

#define DIM  128
#define HID  32
#define KTOT 384          // 3*DIM
#define TPW  16           // edges per wave-tile

typedef __attribute__((ext_vector_type(8))) unsigned short u16x8;
typedef __bf16 bf16x8 __attribute__((ext_vector_type(8)));
typedef __attribute__((ext_vector_type(4))) float f32x4;

static __device__ inline float b2f(unsigned short u) {
    return __uint_as_float(((unsigned)u) << 16);
}
static __device__ inline unsigned short f2bf(float f) {
    unsigned u = __float_as_uint(f);
    return (unsigned short)((u + 0x7fff + ((u >> 16) & 1)) >> 16);  // RNE
}

// ---------------------------------------------------------------------------
// Kernel 0 "prep0": blocks 0..31  -> wsum[r] = sum_d W[r][d] (1 row per wave)
//                   blocks 32..79 -> w1T[h][k] = bf16(w1[k][h])  (384x32)
// (einsum 'ed,ef->e' factorizes: bilinear[e] = (z_src.wsum)*(sum z_dst))
// ---------------------------------------------------------------------------
__global__ __launch_bounds__(256) void prep0_kernel(
    const float* __restrict__ W, const float* __restrict__ w1,
    float* __restrict__ wsum, unsigned short* __restrict__ w1T)
{
    const int b = blockIdx.x;
    const int tid = threadIdx.x;
    if (b < 32) {
        const int wv = tid >> 6, lane = tid & 63;
        const int r = b * 4 + wv;                 // 0..127
        float2 v = *(const float2*)(W + (size_t)r * DIM + lane * 2);
        float s = v.x + v.y;
        s += __shfl_xor(s, 1);  s += __shfl_xor(s, 2);  s += __shfl_xor(s, 4);
        s += __shfl_xor(s, 8);  s += __shfl_xor(s, 16); s += __shfl_xor(s, 32);
        if (lane == 0) wsum[r] = s;
    } else {
        const int idx = (b - 32) * 256 + tid;     // 0..12287 exact
        const int k = idx >> 5, h = idx & 31;
        w1T[(size_t)h * KTOT + k] = f2bf(w1[idx]);
    }
}

// ---------------------------------------------------------------------------
// Kernel 1: per-node: zb16[n][:] = bf16(z[n][:]), s1[n] = z.wsum, s2[n] = sum z
// (unchanged from R2 — validated)
// ---------------------------------------------------------------------------
__global__ __launch_bounds__(256) void node_precompute(
    const float* __restrict__ z, const float* __restrict__ wsum,
    unsigned short* __restrict__ zb16,
    float* __restrict__ s1, float* __restrict__ s2, int nNodes)
{
    const int tid = threadIdx.x;
    const int n = blockIdx.x * 64 + (tid >> 2);
    const int q = tid & 3;
    if (n >= nNodes) return;

    const float* zr = z + (size_t)n * DIM + q * 32;
    const float* wr = wsum + q * 32;
    unsigned short* zo = zb16 + (size_t)n * DIM + q * 32;

    float a1 = 0.f, a2 = 0.f;
#pragma unroll
    for (int i = 0; i < 4; i++) {
        float4 v0 = *(const float4*)(zr + i * 8);
        float4 v1 = *(const float4*)(zr + i * 8 + 4);
        float4 w0 = *(const float4*)(wr + i * 8);
        float4 w1v = *(const float4*)(wr + i * 8 + 4);
        a1 += v0.x * w0.x + v0.y * w0.y + v0.z * w0.z + v0.w * w0.w
            + v1.x * w1v.x + v1.y * w1v.y + v1.z * w1v.z + v1.w * w1v.w;
        a2 += v0.x + v0.y + v0.z + v0.w + v1.x + v1.y + v1.z + v1.w;
        u16x8 o;
        o[0] = f2bf(v0.x); o[1] = f2bf(v0.y); o[2] = f2bf(v0.z); o[3] = f2bf(v0.w);
        o[4] = f2bf(v1.x); o[5] = f2bf(v1.y); o[6] = f2bf(v1.z); o[7] = f2bf(v1.w);
        *(u16x8*)(zo + i * 8) = o;
    }
    a1 += __shfl_xor(a1, 1); a1 += __shfl_xor(a1, 2);
    a2 += __shfl_xor(a2, 1); a2 += __shfl_xor(a2, 2);
    if (q == 0) { s1[n] = a1; s2[n] = a2; }
}

// ---------------------------------------------------------------------------
// Kernel 2: edge kernel — wave-autonomous, ZERO barriers, ZERO LDS.
// Each wave owns 16 edges/tile. A-fragments (16B) gathered straight from
// global (16 lanes cover a 256B bf16 row); product-block A-frag computed
// in registers (elementwise zs*zd); B = w1^T held in 96 VGPRs per wave.
// MFMA 16x16x32 layouts identical to the R2-validated kernel.
// ---------------------------------------------------------------------------
__global__ __launch_bounds__(256, 3) void edge_kernel(
    const unsigned short* __restrict__ zb16, const int* __restrict__ ei,
    const float* __restrict__ s1, const float* __restrict__ s2,
    const unsigned short* __restrict__ w1T, const float* __restrict__ b1,
    const float* __restrict__ w2, const float* __restrict__ b2,
    const float* __restrict__ bias, float* __restrict__ out,
    int nE, int nTiles)
{
    const int lane = threadIdx.x & 63;
    const int wv   = threadIdx.x >> 6;
    const int l15  = lane & 15;
    const int quad = lane >> 4;

    // --- B fragments: B[k][n] with n=l15 (h), k=quad*8+j within each 32-step
    bf16x8 B0[12], B1[12];
    {
        const unsigned short* b0p = w1T + (size_t)l15 * KTOT + quad * 8;
        const unsigned short* b1p = w1T + (size_t)(16 + l15) * KTOT + quad * 8;
#pragma unroll
        for (int s = 0; s < 12; s++) {
            B0[s] = __builtin_bit_cast(bf16x8, *(const u16x8*)(b0p + s * 32));
            B1[s] = __builtin_bit_cast(bf16x8, *(const u16x8*)(b1p + s * 32));
        }
    }
    const float b1a = b1[l15],      w2a = w2[l15];
    const float b1b = b1[16 + l15], w2b = w2[16 + l15];
    const float cbias = bias[0] + b2[0];

    const int wid = blockIdx.x * 4 + wv;
    const int nW  = gridDim.x * 4;

    for (int t = wid; t < nTiles; t += nW) {
        const int e0 = t * TPW;
        const int e  = e0 + l15;
        const bool valid = (e < nE);
        int src = 0, dst = 0;
        if (valid) { src = ei[e]; dst = ei[nE + e]; }
        const float bil = s1[src] * s2[dst];   // lane l15 holds bil for edge l15

        // --- gather A fragments: lane (quad,l15): row of edge l15, 16B chunks
        const unsigned short* zs_p = zb16 + (size_t)src * DIM + quad * 8;
        const unsigned short* zd_p = zb16 + (size_t)dst * DIM + quad * 8;
        u16x8 zs[4], zd[4];
#pragma unroll
        for (int k = 0; k < 4; k++) {
            zs[k] = *(const u16x8*)(zs_p + k * 32);
            zd[k] = *(const u16x8*)(zd_p + k * 32);
        }

        f32x4 acc0 = {0.f, 0.f, 0.f, 0.f}, acc1 = {0.f, 0.f, 0.f, 0.f};
#pragma unroll
        for (int k = 0; k < 4; k++) {          // zs block (K 0..127)
            bf16x8 a = __builtin_bit_cast(bf16x8, zs[k]);
            acc0 = __builtin_amdgcn_mfma_f32_16x16x32_bf16(a, B0[k], acc0, 0, 0, 0);
            acc1 = __builtin_amdgcn_mfma_f32_16x16x32_bf16(a, B1[k], acc1, 0, 0, 0);
        }
#pragma unroll
        for (int k = 0; k < 4; k++) {          // zd block (K 128..255)
            bf16x8 a = __builtin_bit_cast(bf16x8, zd[k]);
            acc0 = __builtin_amdgcn_mfma_f32_16x16x32_bf16(a, B0[4 + k], acc0, 0, 0, 0);
            acc1 = __builtin_amdgcn_mfma_f32_16x16x32_bf16(a, B1[4 + k], acc1, 0, 0, 0);
        }
#pragma unroll
        for (int k = 0; k < 4; k++) {          // product block (K 256..383)
            u16x8 p;
#pragma unroll
            for (int j = 0; j < 8; j++) p[j] = f2bf(b2f(zs[k][j]) * b2f(zd[k][j]));
            bf16x8 a = __builtin_bit_cast(bf16x8, p);
            acc0 = __builtin_amdgcn_mfma_f32_16x16x32_bf16(a, B0[8 + k], acc0, 0, 0, 0);
            acc1 = __builtin_amdgcn_mfma_f32_16x16x32_bf16(a, B1[8 + k], acc1, 0, 0, 0);
        }

        // --- epilogue: C/D col=l15 (h), row=quad*4+r (edge). Reduce over h.
#pragma unroll
        for (int r = 0; r < 4; r++) {
            float v = fmaxf(acc0[r] + b1a, 0.f) * w2a
                    + fmaxf(acc1[r] + b1b, 0.f) * w2b;
            v += __shfl_xor(v, 1); v += __shfl_xor(v, 2);
            v += __shfl_xor(v, 4); v += __shfl_xor(v, 8);
            const int eL = quad * 4 + r;               // edge this sum belongs to
            const float bilr = __shfl(bil, eL);        // from lane eL
            if (l15 == r && (e0 + eL) < nE)
                out[e0 + eL] = v + bilr + cbias;
        }
    }
}

// ---------------------------------------------------------------------------
// Workspace: zb16 ushort[nNodes*128] | w1T ushort[32*384] | s1 | s2 | wsum[128]
// ~26.5 MB for nNodes=100000.
// ---------------------------------------------------------------------------
extern "C" void kernel_launch(void* const* d_in, const int* in_sizes, int n_in,
                              void* d_out, int out_size, void* d_ws, size_t ws_size,
                              hipStream_t stream)
{
    const float* z    = (const float*)d_in[0];
    const int*   ei   = (const int*)d_in[1];
    const float* W    = (const float*)d_in[2];
    const float* bias = (const float*)d_in[3];
    const float* w1   = (const float*)d_in[4];
    const float* b1   = (const float*)d_in[5];
    const float* w2   = (const float*)d_in[6];
    const float* b2   = (const float*)d_in[7];
    float* out = (float*)d_out;

    const int nNodes = in_sizes[0] / DIM;
    const int nE = out_size;

    unsigned short* zb16 = (unsigned short*)d_ws;
    unsigned short* w1T  = zb16 + (size_t)nNodes * DIM;
    float* s1   = (float*)(w1T + (size_t)HID * KTOT);
    float* s2   = s1 + nNodes;
    float* wsum = s2 + nNodes;

    prep0_kernel<<<80, 256, 0, stream>>>(W, w1, wsum, w1T);

    int preBlocks = (nNodes + 63) / 64;
    node_precompute<<<preBlocks, 256, 0, stream>>>(z, wsum, zb16, s1, s2, nNodes);

    const int nTiles = (nE + TPW - 1) / TPW;
    int grid = 1024;
    if (grid * 4 > nTiles) grid = (nTiles + 3) / 4;
    edge_kernel<<<grid, 256, 0, stream>>>(zb16, ei, s1, s2, w1T,
                                          b1, w2, b2, bias, out, nE, nTiles);
}